// Round 12
// baseline (790.045 us; speedup 1.0000x reference)
//
#include <hip/hip_runtime.h>

// CauRecNet: 2-layer LSTM, B=131072 x T=15, FP16 MFMA (f32 accum).
// Round 12: register diet for TRUE 2 blocks/CU: WB1 resident only ks0..3
// (64 regs), ks4/5 streamed from L2 per gate-pair; pair-major l1 (acc 8);
// x-load post-tiles. Target: arch+AGPR total <= 128 -> 4 waves/EU.

typedef float    f32x4 __attribute__((ext_vector_type(4)));
typedef _Float16 f16x8 __attribute__((ext_vector_type(8)));
typedef _Float16 f16x4 __attribute__((ext_vector_type(4)));

#define DEV static __device__ __forceinline__

DEV float fexp2(float x){ return __builtin_amdgcn_exp2f(x); }
DEV float frcp (float x){ return __builtin_amdgcn_rcpf(x); }

#define MFMA16(A,B,C) __builtin_amdgcn_mfma_f32_16x16x32_f16(A,B,C,0,0,0)

constexpr int T = 15, F = 12, CS = 96;
constexpr int R = 32;

// d_ws layout (bytes) — f16 fragments
constexpr int Q1OFF  = 0;        // W1  [wv8][g4][ks6][lane64][16B]
constexpr int Q0HOFF = 196608;   // W0h [grp4][g4][ks2][64][16B]
constexpr int Q0XOFF = 229376;   // W0x [grp4][g4][64][16B]
constexpr int QF2OFF = 245760;   // fc2 [grp8][ks3][64][16B]
constexpr int QF1OFF = 270336;   // fc1 [grp4][ks3][64][16B]

constexpr float NL2E = -1.44269504f, PL2E2 = 2.88539008f;

// LDS map (72KB)
constexpr int OH0 = 0;        // h0: 32 rows x 128B; buf0 @0, buf1 @4096
constexpr int OH1 = 8192;     // h1: 32 rows x 256B; buf0 @8192, buf1 @16384
constexpr int OX  = 24576;    // x : 32 rows x 64B;  buf0 @24576, buf1 @26624
constexpr int OKC = 28672;    // kC1 @+0 (2048), kC0 @+2048 (1024)
constexpr int OWE = 31744;    // wEff floats (129)
constexpr int OWX = 32768;    // W0x frags 16384
constexpr int OC  = 49152;    // c-states [12 slots][512 thr] f32 = 24576
constexpr int LDSB= 73728;

// ---------------- weight pre-quantization -> f16 fragments ----------------
__global__ __launch_bounds__(64) void prequant(
    const float* __restrict__ fc1w, const float* __restrict__ fc2w,
    const float* __restrict__ w0i,  const float* __restrict__ w0h,
    const float* __restrict__ w1i,  const float* __restrict__ w1h,
    char* __restrict__ ws)
{
  const int r = blockIdx.x, j = threadIdx.x;
  auto put = [&](long off, float v){ *(_Float16*)(ws + off) = (_Float16)v; };
  if (r < 512){                       // W1 row n: k-space 192 = [h0(64)|h1(128)]
    int n = r, lr = n & 15, wv = (n & 127) >> 4, g = n >> 7;
    #pragma unroll
    for (int c = 0; c < 3; ++c){
      int k = j + c*64;
      float v = (k < 64) ? w1i[n*64 + k] : w1h[n*128 + (k - 64)];
      int ks = k >> 5, lane = (((k >> 3) & 3) << 4) + lr, jj = k & 7;
      put(Q1OFF + ((long)(((wv*4+g)*6+ks)*64 + lane))*16 + jj*2, v);
    }
  } else if (r < 768){                // W0 row n
    int n = r - 512, lr = n & 15, grp = (n & 63) >> 4, g = n >> 6;
    {
      int k = j;                      // h part, k 0..63
      int ks = k >> 5, lane = (((k >> 3) & 3) << 4) + lr, jj = k & 7;
      put(Q0HOFF + ((long)(((grp*4+g)*2+ks)*64 + lane))*16 + jj*2, w0h[n*64 + k]);
    }
    if (j < 32){                      // x part, k 0..31 (12 real)
      int k = j;
      int lane = (((k >> 3) & 3) << 4) + lr, jj = k & 7;
      float v = (k < 12) ? w0i[n*12 + k] : 0.f;
      put(Q0XOFF + ((long)((grp*4+g)*64 + lane))*16 + jj*2, v);
    }
  } else {                            // fc rows, k-space 96
    bool t2 = (r < 896);
    int n = t2 ? (r - 768) : (r - 896);
    const float* fw = t2 ? fc2w : fc1w;
    long base = t2 ? QF2OFF : QF1OFF;
    int lr = n & 15, grp = n >> 4;
    #pragma unroll
    for (int c = 0; c < 2; ++c){
      int k = j + c*64;
      if (k < 96){
        int ks = k >> 5, lane = (((k >> 3) & 3) << 4) + lr, jj = k & 7;
        put(base + ((long)((grp*3+ks)*64 + lane))*16 + jj*2, fw[n*CS + k]);
      }
    }
  }
}

// 5-exp 2-rcp cell update, overflow-clamped; returns h, updates c (residual).
DEV float cellupd(float t0, float t1, float t2, float t3, float& c){
  float ei = fexp2(t0);
  float ef = fexp2(t1);
  float eg = fexp2(t2);
  float eo = fexp2(t3);
  float e1 = 1.f + ei, e2 = eg + 1.f, e3 = 1.f + ef;
  float m1 = e1 * e2;
  float num = fmaf(c, m1, (eg - 1.f) * e3);
  float tmp = num * frcp(m1 * e3);
  c += tmp;
  float tc = fminf(tmp, 12.0f);
  float ec = fexp2(tc * PL2E2);
  return (ec - 1.f) * frcp((1.f + eo) * (ec + 1.f));
}

// ---------------- main recurrence kernel ----------------
__global__ __launch_bounds__(512, 2) void caurec(
    const float* __restrict__ x,    const float* __restrict__ cs,
    const float* __restrict__ fc1b, const float* __restrict__ fc2b,
    const float* __restrict__ b0i,  const float* __restrict__ b0h,
    const float* __restrict__ b1i,  const float* __restrict__ b1h,
    const float* __restrict__ d1w,  const float* __restrict__ d1b,
    const float* __restrict__ d2w,  const float* __restrict__ d2b,
    const char* __restrict__ ws,    float* __restrict__ out)
{
  __shared__ alignas(16) char L[LDSB];

  const int tid  = threadIdx.x;
  const int wave = tid >> 6, lane = tid & 63, lr = lane & 15, lg = lane >> 4;
  const int n0   = (wave & 3) * 16, mB0 = (wave >> 2) * 16, n1 = wave * 16;
  const int grp  = wave & 3;
  const int rowBase = blockIdx.x * R;
  const int sw8  = (lr & 7) << 4;

  // per-lane bases
  const int rb0   = OH0 + lr*128 + ((lg*16) ^ sw8);    // h0 A-read (+p8 +mt*2048; ^64 = ks1)
  const int rb0w  = rb0 + mB0*128;                     // h0 A-read for the l0 tile
  const int rb1   = OH1 + lr*256 + ((lg*16) ^ sw8);    // h1 A-read (^(hs<<6), +p16 +mt*4096)
  const int xrdb  = OX + (mB0 + lr)*64 + lg*16;        // +px
  const int kadC1 = OKC + wave*256 + lr*16;
  const int kadC0 = OKC + 2048 + grp*256 + lr*16;
  const int cst1  = OH1 + (lg*4)*256 + (((n1 + lr)*2) ^ ((lg & 1) << 6));
  const int cst0  = OH0 + (mB0 + lg*4)*128 + (((n0 + lr)*2) ^ ((lg & 1) << 6));
  const int owxb  = OWX + (grp*4)*1024 + lane*16;      // +g*1024
  const int cbase = OC + tid*4;
  const int xr = tid/3, xq = tid - (tid/3)*3;
  const int xst = OX + xr*64 + xq*8;

  int zro = 0;   // opaque 0: blocks LICM/CSE of per-phase streamed weight loads

  // ---- zero: h0 buf1 + h1 buf0 [4096,16384), x region [24576,28672)
  {
    unsigned* W = (unsigned*)L;
    for (int i = tid; i < 3072; i += 512) W[1024 + i] = 0u;
    for (int i = tid; i < 1024; i += 512) W[6144 + i] = 0u;
  }
  __syncthreads();

  // ---- stage cs -> h1 buf1 (f16, cols 0..95)
  {
    int r = tid >> 4, cq = tid & 15;
    if (cq < 12){
      float4 v0 = *(const float4*)&cs[(size_t)(rowBase + r)*CS + cq*8];
      float4 v1 = *(const float4*)&cs[(size_t)(rowBase + r)*CS + cq*8 + 4];
      f16x8 V;
      V[0]=(_Float16)v0.x; V[1]=(_Float16)v0.y; V[2]=(_Float16)v0.z; V[3]=(_Float16)v0.w;
      V[4]=(_Float16)v1.x; V[5]=(_Float16)v1.y; V[6]=(_Float16)v1.z; V[7]=(_Float16)v1.w;
      int ad = OH1 + 8192 + r*256 + ((cq*16) ^ ((r & 7) << 4));
      *(f16x8*)(L + ad) = V;
    }
  }
  // x(0) -> x buf0
  if (tid < 96){
    float4 v = *(const float4*)&x[((size_t)(rowBase + xr)*T + 0)*F + xq*4];
    f16x4 w; w[0]=(_Float16)v.x; w[1]=(_Float16)v.y; w[2]=(_Float16)v.z; w[3]=(_Float16)v.w;
    *(f16x4*)(L + xst) = w;
  }
  // wEff
  if (tid < 128){
    float s = 0.f;
    for (int a = 0; a < 64; ++a) s += d2w[a] * d1w[a*128 + tid];
    ((float*)(L + OWE))[tid] = s;
  } else if (tid == 128){
    float s = 0.f;
    for (int a = 0; a < 64; ++a) s += d2w[a] * d1b[a];
    ((float*)(L + OWE))[128] = s + d2b[0];
  }
  // kC (per-gate folded bias constants)
  if (lg == 0){
    f32x4 c1k, c0k;
    #pragma unroll
    for (int g = 0; g < 4; ++g){
      float f = (g == 2) ? PL2E2 : NL2E;
      c1k[g] = f * (b1i[g*128 + n1 + lr] + b1h[g*128 + n1 + lr]);
      c0k[g] = f * (b0i[g*64  + n0 + lr] + b0h[g*64  + n0 + lr]);
    }
    *(f32x4*)(L + kadC1) = c1k;
    *(f32x4*)(L + kadC0) = c0k;
  }
  // W0x fragments -> LDS (16KB)
  #pragma unroll
  for (int k = 0; k < 4; ++k){
    int i = tid + k*512;
    *(long*)(L + OWX + i*8) = *(const long*)(ws + Q0XOFF + i*8);
  }
  // W1 fragments ks0..3 -> registers (64 VGPR); ks4,5 streamed from L2
  f16x8 WB1[4][4];
  #pragma unroll
  for (int g = 0; g < 4; ++g)
    #pragma unroll
    for (int ks = 0; ks < 4; ++ks)
      WB1[g][ks] = *(const f16x8*)(ws + Q1OFF + ((long)(((wave*4+g)*6+ks)*64 + lane))*16);
  __syncthreads();

  // ---- init GEMMs (cs in h1 buf1) -> c-states in LDS
  {
    const f32x4 Zf = {0.f,0.f,0.f,0.f};
    float bb2 = fc2b[n1 + lr];
    #pragma unroll
    for (int mt = 0; mt < 2; ++mt){
      f32x4 a = Zf;
      #pragma unroll
      for (int ks = 0; ks < 3; ++ks){
        f16x8 A = *(const f16x8*)(L + ((rb1 ^ (ks << 6)) + 8192 + mt*4096));
        f16x8 B = *(const f16x8*)(ws + QF2OFF + ((long)((wave*3+ks)*64 + lane))*16);
        a = MFMA16(A, B, a);
      }
      #pragma unroll
      for (int e = 0; e < 4; ++e)
        *(float*)(L + cbase + (mt*4 + e)*2048) = a[e] + bb2;
    }
    float bb1 = fc1b[n0 + lr];
    {
      f32x4 a = Zf;
      #pragma unroll
      for (int ks = 0; ks < 3; ++ks){
        f16x8 A = *(const f16x8*)(L + ((rb1 ^ (ks << 6)) + 8192 + mB0*256));
        f16x8 B = *(const f16x8*)(ws + QF1OFF + ((long)((grp*3+ks)*64 + lane))*16);
        a = MFMA16(A, B, a);
      }
      #pragma unroll
      for (int e = 0; e < 4; ++e)
        *(float*)(L + cbase + (8 + e)*2048) = a[e] + bb1;
    }
  }
  __syncthreads();

  // ---- tile lambdas
  auto l1_one = [&](int mt, int p8, int p16, int q16){
    const f32x4 Zf = {0.f,0.f,0.f,0.f};
    f32x4 kC = *(const f32x4*)(L + kadC1);
    const char* w1p = ws + (long)(Q1OFF + zro) + (long)lane*16;
    float tg0[4], tg1[4], tg2[4], tg3[4];
    #pragma unroll
    for (int gp = 0; gp < 2; ++gp){
      const int ga = 2*gp, gb = 2*gp + 1;
      // streamed ks4/5 fragments for this gate pair (L2-resident)
      f16x8 Wa4 = *(const f16x8*)(w1p + (long)(((wave*4+ga)*6+4)*64)*16);
      f16x8 Wa5 = *(const f16x8*)(w1p + (long)(((wave*4+ga)*6+5)*64)*16);
      f16x8 Wb4 = *(const f16x8*)(w1p + (long)(((wave*4+gb)*6+4)*64)*16);
      f16x8 Wb5 = *(const f16x8*)(w1p + (long)(((wave*4+gb)*6+5)*64)*16);
      f16x8 H = *(const f16x8*)(L + (rb0 + p8 + mt*2048));
      f32x4 aA = MFMA16(H, WB1[ga][0], Zf);
      f32x4 aB = MFMA16(H, WB1[gb][0], Zf);
      H = *(const f16x8*)(L + ((rb0 ^ 64) + p8 + mt*2048));
      aA = MFMA16(H, WB1[ga][1], aA); aB = MFMA16(H, WB1[gb][1], aB);
      H = *(const f16x8*)(L + (rb1 + p16 + mt*4096));
      aA = MFMA16(H, WB1[ga][2], aA); aB = MFMA16(H, WB1[gb][2], aB);
      H = *(const f16x8*)(L + ((rb1 ^ 64) + p16 + mt*4096));
      aA = MFMA16(H, WB1[ga][3], aA); aB = MFMA16(H, WB1[gb][3], aB);
      H = *(const f16x8*)(L + ((rb1 ^ 128) + p16 + mt*4096));
      aA = MFMA16(H, Wa4, aA); aB = MFMA16(H, Wb4, aB);
      H = *(const f16x8*)(L + ((rb1 ^ 192) + p16 + mt*4096));
      aA = MFMA16(H, Wa5, aA); aB = MFMA16(H, Wb5, aB);
      float fa = (ga == 2) ? PL2E2 : NL2E;
      #pragma unroll
      for (int e = 0; e < 4; ++e){
        float tA = fmaf(aA[e], fa,   kC[ga]);
        float tB = fmaf(aB[e], NL2E, kC[gb]);
        if (gp == 0){ tg0[e] = tA; tg1[e] = tB; }
        else        { tg2[e] = tA; tg3[e] = tB; }
      }
    }
    const int sb = cst1 + q16 + mt*4096;
    #pragma unroll
    for (int e = 0; e < 4; ++e){
      float cc = *(const float*)(L + cbase + (mt*4 + e)*2048);
      float h = cellupd(tg0[e], tg1[e], tg2[e], tg3[e], cc);
      *(float*)(L + cbase + (mt*4 + e)*2048) = cc;
      *(_Float16*)(L + ((sb + e*256) ^ (e << 4))) = (_Float16)h;
    }
  };

  auto l0_one = [&](int p8, int px, int q8){
    const f32x4 Zf = {0.f,0.f,0.f,0.f};
    f32x4 kC = *(const f32x4*)(L + kadC0);
    f16x8 X  = *(const f16x8*)(L + (xrdb + px));
    f16x8 H0 = *(const f16x8*)(L + (rb0w + p8));
    f16x8 H1 = *(const f16x8*)(L + ((rb0w ^ 64) + p8));
    const char* whp = ws + (long)(Q0HOFF + zro) + (long)(grp*8)*1024 + (long)lane*16;
    float tg0[4], tg1[4], tg2[4], tg3[4];
    #pragma unroll
    for (int g = 0; g < 4; ++g){
      f16x8 W0 = *(const f16x8*)(whp + (g*2+0)*1024);
      f16x8 W1 = *(const f16x8*)(whp + (g*2+1)*1024);
      f16x8 Wx = *(const f16x8*)(L + owxb + g*1024);
      f32x4 a = MFMA16(H0, W0, Zf);
      a = MFMA16(H1, W1, a);
      a = MFMA16(X,  Wx, a);
      float f = (g == 2) ? PL2E2 : NL2E;
      float* tg = (g==0)?tg0:(g==1)?tg1:(g==2)?tg2:tg3;
      #pragma unroll
      for (int e = 0; e < 4; ++e) tg[e] = fmaf(a[e], f, kC[g]);
    }
    const int sb = cst0 + q8;
    #pragma unroll
    for (int e = 0; e < 4; ++e){
      float cc = *(const float*)(L + cbase + (8 + e)*2048);
      float h = cellupd(tg0[e], tg1[e], tg2[e], tg3[e], cc);
      *(float*)(L + cbase + (8 + e)*2048) = cc;
      *(_Float16*)(L + ((sb + e*128) ^ (e << 4))) = (_Float16)h;
    }
  };

  auto stageX = [&](int t, int ofs){
    if (tid < 96){
      float4 v = *(const float4*)&x[((size_t)(rowBase + xr)*T + t)*F + xq*4];
      f16x4 w; w[0]=(_Float16)v.x; w[1]=(_Float16)v.y; w[2]=(_Float16)v.z; w[3]=(_Float16)v.w;
      *(f16x4*)(L + xst + ofs) = w;
    }
  };

  // ---- pre-loop: L0(0): h0(-1)=zeros(buf1), x(0)(buf0) -> h0(0)->buf0; stage x(1)->buf1
  {
    l0_one(4096, 0, 0);
    stageX(1, 2048);
    __syncthreads();
  }

  // ---- main loop: M(i) = L1(i) + L0(i+1); 1 barrier/step
  for (int j = 0; j < 7; ++j){
    { // M(2j): reads h0/h1 buf0, x buf1; writes buf1; stage x(2j+2)->buf0
      asm volatile("" : "+v"(zro));
      l1_one(0, 0, 0, 8192);
      l1_one(1, 0, 0, 8192);
      l0_one(0, 2048, 4096);
      stageX(2*j + 2, 0);
      __syncthreads();
    }
    { // M(2j+1): reads buf1, x buf0; writes buf0; stage x(2j+3)->buf1 (j<6)
      asm volatile("" : "+v"(zro));
      l1_one(0, 4096, 8192, 0);
      l1_one(1, 4096, 8192, 0);
      l0_one(4096, 0, 0);
      if (j < 6) stageX(2*j + 3, 2048);
      __syncthreads();
    }
  }

  // ---- final: L1(14) (reads buf0) -> h1(15) into buf1
  {
    asm volatile("" : "+v"(zro));
    l1_one(0, 0, 0, 8192);
    l1_one(1, 0, 0, 8192);
    __syncthreads();
  }

  // ---- epilogue: pred = h1 . w_eff + b_eff (h1 f16 in buf1)
  {
    int r = tid >> 4, s = tid & 15;
    const float* wE = (const float*)(L + OWE);
    float sum = 0.f;
    #pragma unroll
    for (int cc = 0; cc < 8; ++cc){
      int c = s*8 + cc;
      const char* pe = L + OH1 + 8192 + r*256 + ((c*2) ^ ((r & 7) << 4));
      sum += (float)(*(const _Float16*)pe) * wE[c];
    }
    sum += __shfl_down(sum, 8);
    sum += __shfl_down(sum, 4);
    sum += __shfl_down(sum, 2);
    sum += __shfl_down(sum, 1);
    if (s == 0) out[rowBase + r] = sum + wE[128];
  }
}

extern "C" void kernel_launch(void* const* d_in, const int* in_sizes, int n_in,
                              void* d_out, int out_size, void* d_ws, size_t ws_size,
                              hipStream_t stream) {
  const float* x    = (const float*)d_in[0];
  const float* cs   = (const float*)d_in[1];
  const float* fc1w = (const float*)d_in[2];
  const float* fc1b = (const float*)d_in[3];
  const float* fc2w = (const float*)d_in[4];
  const float* fc2b = (const float*)d_in[5];
  const float* w0i  = (const float*)d_in[6];
  const float* w0h  = (const float*)d_in[7];
  const float* b0i  = (const float*)d_in[8];
  const float* b0h  = (const float*)d_in[9];
  const float* w1i  = (const float*)d_in[10];
  const float* w1h  = (const float*)d_in[11];
  const float* b1i  = (const float*)d_in[12];
  const float* b1h  = (const float*)d_in[13];
  const float* d1w  = (const float*)d_in[14];
  const float* d1b  = (const float*)d_in[15];
  const float* d2w  = (const float*)d_in[16];
  const float* d2b  = (const float*)d_in[17];

  char* ws = (char*)d_ws;
  prequant<<<960, 64, 0, stream>>>(fc1w, fc2w, w0i, w0h, w1i, w1h, ws);

  const int Btot = in_sizes[0] / (T * F);   // 131072
  const int grid = Btot / R;                // 4096
  caurec<<<grid, 512, 0, stream>>>(x, cs, fc1b, fc2b, b0i, b0h, b1i, b1h,
                                   d1w, d1b, d2w, d2b, ws, (float*)d_out);
}

// Round 13
// 699.380 us; speedup vs baseline: 1.1296x; 1.1296x over previous
//
#include <hip/hip_runtime.h>

// CauRecNet: 2-layer LSTM, B=131072 x T=15, FP16 MFMA (f32 accum).
// Round 13: R=64 (round-9 geometry) + full register residency: W1 (96) + W0h
// (32) + W0x (16) + c-states (24) + kC (8) in regs. Occupancy is structurally
// 1 block/CU (AGPR-inclusive 128-cap unreachable) -> spend regs to cut
// VALU/LDS issue instead. LDS 57KB: h0/h1/x double-buffers + wEff only.

typedef float    f32x4 __attribute__((ext_vector_type(4)));
typedef _Float16 f16x8 __attribute__((ext_vector_type(8)));
typedef _Float16 f16x4 __attribute__((ext_vector_type(4)));

#define DEV static __device__ __forceinline__

DEV float fexp2(float x){ return __builtin_amdgcn_exp2f(x); }
DEV float frcp (float x){ return __builtin_amdgcn_rcpf(x); }

#define MFMA16(A,B,C) __builtin_amdgcn_mfma_f32_16x16x32_f16(A,B,C,0,0,0)

constexpr int T = 15, F = 12, CS = 96;
constexpr int R = 64;

// d_ws layout (bytes) — f16 fragments
constexpr int Q1OFF  = 0;        // W1  [wv8][g4][ks6][lane64][16B]
constexpr int Q0HOFF = 196608;   // W0h [grp4][g4][ks2][64][16B]
constexpr int Q0XOFF = 229376;   // W0x [grp4][g4][64][16B]
constexpr int QF2OFF = 245760;   // fc2 [grp8][ks3][64][16B]
constexpr int QF1OFF = 270336;   // fc1 [grp4][ks3][64][16B]

constexpr float NL2E = -1.44269504f, PL2E2 = 2.88539008f;

// LDS map (57KB)
constexpr int OH0 = 0;        // h0: 64 rows x 128B; buf0 @0, buf1 @8192
constexpr int OH1 = 16384;    // h1: 64 rows x 256B; buf0 @+0, buf1 @+16384
constexpr int OX  = 49152;    // x : 64 rows x 64B;  buf0 @+0, buf1 @+4096
constexpr int OWE = 57344;    // wEff floats (129)
constexpr int LDSB= 58368;

// ---------------- weight pre-quantization -> f16 fragments ----------------
__global__ __launch_bounds__(64) void prequant(
    const float* __restrict__ fc1w, const float* __restrict__ fc2w,
    const float* __restrict__ w0i,  const float* __restrict__ w0h,
    const float* __restrict__ w1i,  const float* __restrict__ w1h,
    char* __restrict__ ws)
{
  const int r = blockIdx.x, j = threadIdx.x;
  auto put = [&](long off, float v){ *(_Float16*)(ws + off) = (_Float16)v; };
  if (r < 512){                       // W1 row n: k-space 192 = [h0(64)|h1(128)]
    int n = r, lr = n & 15, wv = (n & 127) >> 4, g = n >> 7;
    #pragma unroll
    for (int c = 0; c < 3; ++c){
      int k = j + c*64;
      float v = (k < 64) ? w1i[n*64 + k] : w1h[n*128 + (k - 64)];
      int ks = k >> 5, lane = (((k >> 3) & 3) << 4) + lr, jj = k & 7;
      put(Q1OFF + ((long)(((wv*4+g)*6+ks)*64 + lane))*16 + jj*2, v);
    }
  } else if (r < 768){                // W0 row n
    int n = r - 512, lr = n & 15, grp = (n & 63) >> 4, g = n >> 6;
    {
      int k = j;                      // h part, k 0..63
      int ks = k >> 5, lane = (((k >> 3) & 3) << 4) + lr, jj = k & 7;
      put(Q0HOFF + ((long)(((grp*4+g)*2+ks)*64 + lane))*16 + jj*2, w0h[n*64 + k]);
    }
    if (j < 32){                      // x part, k 0..31 (12 real)
      int k = j;
      int lane = (((k >> 3) & 3) << 4) + lr, jj = k & 7;
      float v = (k < 12) ? w0i[n*12 + k] : 0.f;
      put(Q0XOFF + ((long)((grp*4+g)*64 + lane))*16 + jj*2, v);
    }
  } else {                            // fc rows, k-space 96
    bool t2 = (r < 896);
    int n = t2 ? (r - 768) : (r - 896);
    const float* fw = t2 ? fc2w : fc1w;
    long base = t2 ? QF2OFF : QF1OFF;
    int lr = n & 15, grp = n >> 4;
    #pragma unroll
    for (int c = 0; c < 2; ++c){
      int k = j + c*64;
      if (k < 96){
        int ks = k >> 5, lane = (((k >> 3) & 3) << 4) + lr, jj = k & 7;
        put(base + ((long)((grp*3+ks)*64 + lane))*16 + jj*2, fw[n*CS + k]);
      }
    }
  }
}

// 5-exp 2-rcp cell update, overflow-clamped; returns h, updates c (residual).
DEV float cellupd(float t0, float t1, float t2, float t3, float& c){
  float ei = fexp2(t0);
  float ef = fexp2(t1);
  float eg = fexp2(t2);
  float eo = fexp2(t3);
  float e1 = 1.f + ei, e2 = eg + 1.f, e3 = 1.f + ef;
  float m1 = e1 * e2;
  float num = fmaf(c, m1, (eg - 1.f) * e3);
  float tmp = num * frcp(m1 * e3);
  c += tmp;
  float tc = fminf(tmp, 12.0f);
  float ec = fexp2(tc * PL2E2);
  return (ec - 1.f) * frcp((1.f + eo) * (ec + 1.f));
}

// ---------------- main recurrence kernel ----------------
__global__ __launch_bounds__(512, 2) void caurec(
    const float* __restrict__ x,    const float* __restrict__ cs,
    const float* __restrict__ fc1b, const float* __restrict__ fc2b,
    const float* __restrict__ b0i,  const float* __restrict__ b0h,
    const float* __restrict__ b1i,  const float* __restrict__ b1h,
    const float* __restrict__ d1w,  const float* __restrict__ d1b,
    const float* __restrict__ d2w,  const float* __restrict__ d2b,
    const char* __restrict__ ws,    float* __restrict__ out)
{
  __shared__ alignas(16) char L[LDSB];

  const int tid  = threadIdx.x;
  const int wave = tid >> 6, lane = tid & 63, lr = lane & 15, lg = lane >> 4;
  const int n0   = (wave & 3) * 16, mB0 = (wave >> 2) * 32, n1 = wave * 16;
  const int grp  = wave & 3;
  const int rowBase = blockIdx.x * R;
  const int sw8  = (lr & 7) << 4;

  // per-lane bases
  const int rb0   = OH0 + lr*128 + ((lg*16) ^ sw8);    // h0 A-read (+p8 +mt*2048; ^64 = ks1)
  const int rb0w  = rb0 + mB0*128;                     // h0 A-read for l0 tiles
  const int rb1   = OH1 + lr*256 + ((lg*16) ^ sw8);    // h1 A-read (^(ks<<6), +p16 +mt*4096)
  const int xrdb  = OX + (mB0 + lr)*64 + lg*16;        // +px +mt*1024
  const int cst1  = OH1 + (lg*4)*256 + (((n1 + lr)*2) ^ ((lg & 1) << 6));
  const int cst0  = OH0 + (mB0 + lg*4)*128 + (((n0 + lr)*2) ^ ((lg & 1) << 6));
  const int xr = tid/3, xq = tid - (tid/3)*3;
  const int xst = OX + xr*64 + xq*8;

  // ---- zero: h0 buf1 [8192,16384), h1 buf0 [16384,32768), x [49152,57344)
  {
    unsigned* W = (unsigned*)L;
    for (int i = tid; i < 2048; i += 512) W[2048  + i] = 0u;
    for (int i = tid; i < 4096; i += 512) W[4096  + i] = 0u;
    for (int i = tid; i < 2048; i += 512) W[12288 + i] = 0u;
  }
  __syncthreads();

  // ---- stage cs -> h1 buf1 (f16, cols 0..127, zeros >=96)
  {
    int r = tid >> 3, cg = (tid & 7) * 16;
    #pragma unroll
    for (int u = 0; u < 2; ++u){
      f16x8 V;
      #pragma unroll
      for (int q4 = 0; q4 < 2; ++q4){
        int col = cg + u*8 + q4*4;
        float4 v = make_float4(0.f,0.f,0.f,0.f);
        if (col < CS) v = *(const float4*)&cs[(size_t)(rowBase + r)*CS + col];
        V[q4*4+0]=(_Float16)v.x; V[q4*4+1]=(_Float16)v.y;
        V[q4*4+2]=(_Float16)v.z; V[q4*4+3]=(_Float16)v.w;
      }
      int ad = OH1 + 16384 + r*256 + (((cg + u*8)*2) ^ ((r & 7) << 4));
      *(f16x8*)(L + ad) = V;
    }
  }
  // x(0) -> x buf0
  if (tid < 192){
    float4 v = *(const float4*)&x[((size_t)(rowBase + xr)*T + 0)*F + xq*4];
    f16x4 w; w[0]=(_Float16)v.x; w[1]=(_Float16)v.y; w[2]=(_Float16)v.z; w[3]=(_Float16)v.w;
    *(f16x4*)(L + xst) = w;
  }
  // wEff
  if (tid < 128){
    float s = 0.f;
    for (int a = 0; a < 64; ++a) s += d2w[a] * d1w[a*128 + tid];
    ((float*)(L + OWE))[tid] = s;
  } else if (tid == 128){
    float s = 0.f;
    for (int a = 0; a < 64; ++a) s += d2w[a] * d1b[a];
    ((float*)(L + OWE))[128] = s + d2b[0];
  }
  // kC (per-gate folded bias constants) -> registers
  f32x4 kC1v, kC0v;
  #pragma unroll
  for (int g = 0; g < 4; ++g){
    float f = (g == 2) ? PL2E2 : NL2E;
    kC1v[g] = f * (b1i[g*128 + n1 + lr] + b1h[g*128 + n1 + lr]);
    kC0v[g] = f * (b0i[g*64  + n0 + lr] + b0h[g*64  + n0 + lr]);
  }
  // weight fragments -> registers: W1 (96), W0h (32), W0x (16)
  f16x8 WB1[4][6];
  #pragma unroll
  for (int g = 0; g < 4; ++g)
    #pragma unroll
    for (int ks = 0; ks < 6; ++ks)
      WB1[g][ks] = *(const f16x8*)(ws + Q1OFF + ((long)(((wave*4+g)*6+ks)*64 + lane))*16);
  f16x8 WB0h[4][2], WB0x[4];
  #pragma unroll
  for (int g = 0; g < 4; ++g){
    #pragma unroll
    for (int sp = 0; sp < 2; ++sp)
      WB0h[g][sp] = *(const f16x8*)(ws + Q0HOFF + ((long)(((grp*4+g)*2+sp)*64 + lane))*16);
    WB0x[g] = *(const f16x8*)(ws + Q0XOFF + ((long)((grp*4+g)*64 + lane))*16);
  }
  __syncthreads();

  // ---- init GEMMs (cs in h1 buf1) -> c-states in registers
  f32x4 c1r[4], c0r[2];
  {
    const f32x4 Zf = {0.f,0.f,0.f,0.f};
    float bb2 = fc2b[n1 + lr];
    #pragma unroll
    for (int mt = 0; mt < 4; ++mt){
      f32x4 a = Zf;
      #pragma unroll
      for (int ks = 0; ks < 3; ++ks){
        f16x8 A = *(const f16x8*)(L + ((rb1 ^ (ks << 6)) + 16384 + mt*4096));
        f16x8 B = *(const f16x8*)(ws + QF2OFF + ((long)((wave*3+ks)*64 + lane))*16);
        a = MFMA16(A, B, a);
      }
      #pragma unroll
      for (int e = 0; e < 4; ++e) c1r[mt][e] = a[e] + bb2;
    }
    float bb1 = fc1b[n0 + lr];
    #pragma unroll
    for (int mt = 0; mt < 2; ++mt){
      f32x4 a = Zf;
      #pragma unroll
      for (int ks = 0; ks < 3; ++ks){
        f16x8 A = *(const f16x8*)(L + ((rb1 ^ (ks << 6)) + 16384 + mB0*256 + mt*4096));
        f16x8 B = *(const f16x8*)(ws + QF1OFF + ((long)((grp*3+ks)*64 + lane))*16);
        a = MFMA16(A, B, a);
      }
      #pragma unroll
      for (int e = 0; e < 4; ++e) c0r[mt][e] = a[e] + bb1;
    }
  }
  __syncthreads();

  // ---- tile lambdas
  auto l1_one = [&](int mt, int p8, int p16, int q16){
    const f32x4 Zf = {0.f,0.f,0.f,0.f};
    f16x8 H = *(const f16x8*)(L + (rb0 + p8 + mt*2048));
    f32x4 a0 = MFMA16(H, WB1[0][0], Zf);
    f32x4 a1 = MFMA16(H, WB1[1][0], Zf);
    f32x4 a2 = MFMA16(H, WB1[2][0], Zf);
    f32x4 a3 = MFMA16(H, WB1[3][0], Zf);
    H = *(const f16x8*)(L + ((rb0 ^ 64) + p8 + mt*2048));
    a0 = MFMA16(H, WB1[0][1], a0); a1 = MFMA16(H, WB1[1][1], a1);
    a2 = MFMA16(H, WB1[2][1], a2); a3 = MFMA16(H, WB1[3][1], a3);
    #pragma unroll
    for (int ks = 0; ks < 4; ++ks){
      H = *(const f16x8*)(L + ((rb1 ^ (ks << 6)) + p16 + mt*4096));
      a0 = MFMA16(H, WB1[0][2+ks], a0); a1 = MFMA16(H, WB1[1][2+ks], a1);
      a2 = MFMA16(H, WB1[2][2+ks], a2); a3 = MFMA16(H, WB1[3][2+ks], a3);
    }
    const int sb = cst1 + q16 + mt*4096;
    #pragma unroll
    for (int e = 0; e < 4; ++e){
      float t0 = fmaf(a0[e], NL2E,  kC1v[0]);
      float t1 = fmaf(a1[e], NL2E,  kC1v[1]);
      float t2 = fmaf(a2[e], PL2E2, kC1v[2]);
      float t3 = fmaf(a3[e], NL2E,  kC1v[3]);
      float cc = c1r[mt][e];
      float h = cellupd(t0, t1, t2, t3, cc);
      c1r[mt][e] = cc;
      *(_Float16*)(L + ((sb + e*256) ^ (e << 4))) = (_Float16)h;
    }
  };

  auto l0_one = [&](int mt, int p8, int px, int q8){
    const f32x4 Zf = {0.f,0.f,0.f,0.f};
    f16x8 X  = *(const f16x8*)(L + (xrdb + px + mt*1024));
    f16x8 H0 = *(const f16x8*)(L + (rb0w + p8 + mt*2048));
    f16x8 H1 = *(const f16x8*)(L + ((rb0w ^ 64) + p8 + mt*2048));
    f32x4 a0 = MFMA16(H0, WB0h[0][0], Zf);
    f32x4 a1 = MFMA16(H0, WB0h[1][0], Zf);
    f32x4 a2 = MFMA16(H0, WB0h[2][0], Zf);
    f32x4 a3 = MFMA16(H0, WB0h[3][0], Zf);
    a0 = MFMA16(H1, WB0h[0][1], a0); a1 = MFMA16(H1, WB0h[1][1], a1);
    a2 = MFMA16(H1, WB0h[2][1], a2); a3 = MFMA16(H1, WB0h[3][1], a3);
    a0 = MFMA16(X, WB0x[0], a0); a1 = MFMA16(X, WB0x[1], a1);
    a2 = MFMA16(X, WB0x[2], a2); a3 = MFMA16(X, WB0x[3], a3);
    const int sb = cst0 + q8 + mt*2048;
    #pragma unroll
    for (int e = 0; e < 4; ++e){
      float t0 = fmaf(a0[e], NL2E,  kC0v[0]);
      float t1 = fmaf(a1[e], NL2E,  kC0v[1]);
      float t2 = fmaf(a2[e], PL2E2, kC0v[2]);
      float t3 = fmaf(a3[e], NL2E,  kC0v[3]);
      float cc = c0r[mt][e];
      float h = cellupd(t0, t1, t2, t3, cc);
      c0r[mt][e] = cc;
      *(_Float16*)(L + ((sb + e*128) ^ (e << 4))) = (_Float16)h;
    }
  };

  // ---- pre-loop: L0(0): h0(-1)=zeros(buf1), x(0)(buf0) -> h0(0)->buf0; stage x(1)->buf1
  {
    float4 xv; const bool doX = tid < 192;
    if (doX) xv = *(const float4*)&x[((size_t)(rowBase + xr)*T + 1)*F + xq*4];
    l0_one(0, 8192, 0, 0);
    l0_one(1, 8192, 0, 0);
    if (doX){
      f16x4 w; w[0]=(_Float16)xv.x; w[1]=(_Float16)xv.y; w[2]=(_Float16)xv.z; w[3]=(_Float16)xv.w;
      *(f16x4*)(L + xst + 4096) = w;
    }
    __syncthreads();
  }

  // ---- main loop: M(i) = L1(i) + L0(i+1); 1 barrier/step
  for (int j = 0; j < 7; ++j){
    { // M(2j): reads h0/h1 buf0, x buf1; writes buf1; stage x(2j+2)->buf0
      float4 xv; const bool doX = tid < 192;
      if (doX) xv = *(const float4*)&x[((size_t)(rowBase + xr)*T + (2*j + 2))*F + xq*4];
      l1_one(0, 0, 0, 16384);
      l1_one(1, 0, 0, 16384);
      l0_one(0, 0, 4096, 8192);
      l1_one(2, 0, 0, 16384);
      l0_one(1, 0, 4096, 8192);
      l1_one(3, 0, 0, 16384);
      if (doX){
        f16x4 w; w[0]=(_Float16)xv.x; w[1]=(_Float16)xv.y; w[2]=(_Float16)xv.z; w[3]=(_Float16)xv.w;
        *(f16x4*)(L + xst) = w;
      }
      __syncthreads();
    }
    { // M(2j+1): reads buf1, x buf0; writes buf0; stage x(2j+3)->buf1 (j<6)
      float4 xv; const bool doX = (j < 6) && (tid < 192);
      if (doX) xv = *(const float4*)&x[((size_t)(rowBase + xr)*T + (2*j + 3))*F + xq*4];
      l1_one(0, 8192, 16384, 0);
      l1_one(1, 8192, 16384, 0);
      l0_one(0, 8192, 0, 0);
      l1_one(2, 8192, 16384, 0);
      l0_one(1, 8192, 0, 0);
      l1_one(3, 8192, 16384, 0);
      if (doX){
        f16x4 w; w[0]=(_Float16)xv.x; w[1]=(_Float16)xv.y; w[2]=(_Float16)xv.z; w[3]=(_Float16)xv.w;
        *(f16x4*)(L + xst + 4096) = w;
      }
      __syncthreads();
    }
  }

  // ---- final: L1(14) (reads buf0) -> h1(15) into buf1
  {
    l1_one(0, 0, 0, 16384);
    l1_one(1, 0, 0, 16384);
    l1_one(2, 0, 0, 16384);
    l1_one(3, 0, 0, 16384);
    __syncthreads();
  }

  // ---- epilogue: pred = h1 . w_eff + b_eff (h1 f16 in buf1)
  {
    int r = tid >> 3, s = tid & 7;
    const float* wE = (const float*)(L + OWE);
    float sum = 0.f;
    #pragma unroll
    for (int cc = 0; cc < 16; ++cc){
      int c = s*16 + cc;
      const char* pe = L + OH1 + 16384 + r*256 + ((c*2) ^ ((r & 7) << 4));
      sum += (float)(*(const _Float16*)pe) * wE[c];
    }
    sum += __shfl_down(sum, 4);
    sum += __shfl_down(sum, 2);
    sum += __shfl_down(sum, 1);
    if (s == 0) out[rowBase + r] = sum + wE[128];
  }
}

extern "C" void kernel_launch(void* const* d_in, const int* in_sizes, int n_in,
                              void* d_out, int out_size, void* d_ws, size_t ws_size,
                              hipStream_t stream) {
  const float* x    = (const float*)d_in[0];
  const float* cs   = (const float*)d_in[1];
  const float* fc1w = (const float*)d_in[2];
  const float* fc1b = (const float*)d_in[3];
  const float* fc2w = (const float*)d_in[4];
  const float* fc2b = (const float*)d_in[5];
  const float* w0i  = (const float*)d_in[6];
  const float* w0h  = (const float*)d_in[7];
  const float* b0i  = (const float*)d_in[8];
  const float* b0h  = (const float*)d_in[9];
  const float* w1i  = (const float*)d_in[10];
  const float* w1h  = (const float*)d_in[11];
  const float* b1i  = (const float*)d_in[12];
  const float* b1h  = (const float*)d_in[13];
  const float* d1w  = (const float*)d_in[14];
  const float* d1b  = (const float*)d_in[15];
  const float* d2w  = (const float*)d_in[16];
  const float* d2b  = (const float*)d_in[17];

  char* ws = (char*)d_ws;
  prequant<<<960, 64, 0, stream>>>(fc1w, fc2w, w0i, w0h, w1i, w1h, ws);

  const int Btot = in_sizes[0] / (T * F);   // 131072
  const int grid = Btot / R;                // 2048
  caurec<<<grid, 512, 0, stream>>>(x, cs, fc1b, fc2b, b0i, b0h, b1i, b1h,
                                   d1w, d1b, d2w, d2b, ws, (float*)d_out);
}

// Round 14
// 645.467 us; speedup vs baseline: 1.2240x; 1.0835x over previous
//
#include <hip/hip_runtime.h>

// CauRecNet: 2-layer LSTM, B=131072 x T=15. Round 14 = round 9 verbatim
// (best known: 645us). FP16 MFMA (f32 accum), R=64, W1 frags in regs (120
// VGPR — just under the empirical 128 arch-VGPR clamp), W0h/W0x frags + cell
// states + kC in LDS. Rounds 10-13 (occupancy/residency restructures) all
// regressed; this is the converged configuration.

typedef float    f32x4 __attribute__((ext_vector_type(4)));
typedef _Float16 f16x8 __attribute__((ext_vector_type(8)));
typedef _Float16 f16x4 __attribute__((ext_vector_type(4)));

#define DEV static __device__ __forceinline__

DEV float fexp2(float x){ return __builtin_amdgcn_exp2f(x); }
DEV float frcp (float x){ return __builtin_amdgcn_rcpf(x); }

#define MFMA16(A,B,C) __builtin_amdgcn_mfma_f32_16x16x32_f16(A,B,C,0,0,0)

constexpr int T = 15, F = 12, CS = 96;
constexpr int R = 64;

// d_ws layout (bytes) — f16 fragments
constexpr int Q1OFF  = 0;        // W1  [wv8][g4][ks6][lane64][16B] = 196608
constexpr int Q0HOFF = 196608;   // W0h [grp4][g4][ks2][64][16B]    = 32768
constexpr int Q0XOFF = 229376;   // W0x [grp4][g4][64][16B]         = 16384
constexpr int QF2OFF = 245760;   // fc2 [grp8][ks3][64][16B]        = 24576
constexpr int QF1OFF = 270336;   // fc1 [grp4][ks3][64][16B]        = 12288

constexpr float NL2E = -1.44269504f, PL2E2 = 2.88539008f;

// LDS map
constexpr int OH0 = 0;        // h0: 64 rows x 128B, bufs @0 / @8192
constexpr int OH1 = 16384;    // h1: 64 rows x 256B, bufs @+0 / @+16384
constexpr int OX  = 49152;    // x : 64 rows x 64B (K=32 padded), bufs @+0 / @+4096
constexpr int OKC = 57344;    // kC1 [wave][lr]x16B = 2048; kC0 @+2048 = 1024
constexpr int OWE = 60416;    // wEff floats (129)
constexpr int OWX = 61440;    // W0x frags 16K
constexpr int OWH = 77824;    // W0h frags 32K
constexpr int OC  = 110592;   // c-states [24 slots][512 thr] f32 = 49152
constexpr int LDSB= 159744;

// ---------------- weight pre-quantization -> f16 fragments ----------------
__global__ __launch_bounds__(64) void prequant(
    const float* __restrict__ fc1w, const float* __restrict__ fc2w,
    const float* __restrict__ w0i,  const float* __restrict__ w0h,
    const float* __restrict__ w1i,  const float* __restrict__ w1h,
    char* __restrict__ ws)
{
  const int r = blockIdx.x, j = threadIdx.x;
  auto put = [&](long off, float v){ *(_Float16*)(ws + off) = (_Float16)v; };
  if (r < 512){                       // W1 row n: k-space 192 = [h0(64)|h1(128)]
    int n = r, lr = n & 15, wv = (n & 127) >> 4, g = n >> 7;
    #pragma unroll
    for (int c = 0; c < 3; ++c){
      int k = j + c*64;
      float v = (k < 64) ? w1i[n*64 + k] : w1h[n*128 + (k - 64)];
      int ks = k >> 5, lane = (((k >> 3) & 3) << 4) + lr, jj = k & 7;
      put(Q1OFF + ((long)(((wv*4+g)*6+ks)*64 + lane))*16 + jj*2, v);
    }
  } else if (r < 768){                // W0 row n
    int n = r - 512, lr = n & 15, grp = (n & 63) >> 4, g = n >> 6;
    {
      int k = j;                      // h part, k 0..63
      int ks = k >> 5, lane = (((k >> 3) & 3) << 4) + lr, jj = k & 7;
      put(Q0HOFF + ((long)(((grp*4+g)*2+ks)*64 + lane))*16 + jj*2, w0h[n*64 + k]);
    }
    if (j < 32){                      // x part, k 0..31 (12 real)
      int k = j;
      int lane = (((k >> 3) & 3) << 4) + lr, jj = k & 7;
      float v = (k < 12) ? w0i[n*12 + k] : 0.f;
      put(Q0XOFF + ((long)((grp*4+g)*64 + lane))*16 + jj*2, v);
    }
  } else {                            // fc rows, k-space 96
    bool t2 = (r < 896);
    int n = t2 ? (r - 768) : (r - 896);
    const float* fw = t2 ? fc2w : fc1w;
    long base = t2 ? QF2OFF : QF1OFF;
    int lr = n & 15, grp = n >> 4;
    #pragma unroll
    for (int c = 0; c < 2; ++c){
      int k = j + c*64;
      if (k < 96){
        int ks = k >> 5, lane = (((k >> 3) & 3) << 4) + lr, jj = k & 7;
        put(base + ((long)((grp*3+ks)*64 + lane))*16 + jj*2, fw[n*CS + k]);
      }
    }
  }
}

// 5-exp 2-rcp cell update, overflow-clamped; returns h, updates c (residual).
DEV float cellupd(float t0, float t1, float t2, float t3, float& c){
  float ei = fexp2(t0);                 // e^{-a_i}
  float ef = fexp2(t1);                 // e^{-a_f}
  float eg = fexp2(t2);                 // e^{2 a_g}
  float eo = fexp2(t3);                 // e^{-a_o}
  float e1 = 1.f + ei, e2 = eg + 1.f, e3 = 1.f + ef;
  float m1 = e1 * e2;
  float num = fmaf(c, m1, (eg - 1.f) * e3);
  float tmp = num * frcp(m1 * e3);      // sigma(f)*c + sigma(i)*tanh(g)
  c += tmp;
  float tc = fminf(tmp, 12.0f);
  float ec = fexp2(tc * PL2E2);
  return (ec - 1.f) * frcp((1.f + eo) * (ec + 1.f));  // sigma(o)*tanh(tmp)
}

// ---------------- main recurrence kernel ----------------
__global__ __launch_bounds__(512, 2) void caurec(
    const float* __restrict__ x,    const float* __restrict__ cs,
    const float* __restrict__ fc1b, const float* __restrict__ fc2b,
    const float* __restrict__ b0i,  const float* __restrict__ b0h,
    const float* __restrict__ b1i,  const float* __restrict__ b1h,
    const float* __restrict__ d1w,  const float* __restrict__ d1b,
    const float* __restrict__ d2w,  const float* __restrict__ d2b,
    const char* __restrict__ ws,    float* __restrict__ out)
{
  __shared__ alignas(16) char L[LDSB];

  const int tid  = threadIdx.x;
  const int wave = tid >> 6, lane = tid & 63, lr = lane & 15, lg = lane >> 4;
  const int n0   = (wave & 3) * 16, mB0 = (wave >> 2) * 32, n1 = wave * 16;
  const int grp  = wave & 3;
  const int rowBase = blockIdx.x * R;
  const int sw8  = (lr & 7) << 4;

  // per-lane bases
  const int rb0   = OH0 + lr*128 + ((lg*16) ^ sw8);    // h0 A-read (+p8 +mt*2048; ^64 = ks1)
  const int rb0w  = rb0 + mB0*128;
  const int rb1   = OH1 + lr*256 + ((lg*16) ^ sw8);    // h1 A-read (^ (ks<<6), +p16 +mt*4096)
  const int xrdb  = OX + (mB0 + lr)*64 + lg*16;        // +px +mt*1024
  const int kadC1 = OKC + wave*256 + lr*16;
  const int kadC0 = OKC + 2048 + grp*256 + lr*16;
  const int cst1  = OH1 + (lg*4)*256 + (((n1 + lr)*2) ^ ((lg & 1) << 6));
  const int cst0  = OH0 + (mB0 + lg*4)*128 + (((n0 + lr)*2) ^ ((lg & 1) << 6));
  const int owxb  = OWX + grp*4096 + lane*16;
  const int owhb  = OWH + grp*8192 + lane*16;
  const int cbase = OC + tid*4;
  const int xr = tid/3, xq = tid - (tid/3)*3;
  const int xst = OX + xr*64 + xq*8;

  // ---- zero: h0 buf1, h1 buf0, x both bufs
  {
    unsigned* W = (unsigned*)L;
    for (int i = tid; i < 2048; i += 512) W[2048  + i] = 0u;   // [8192,16384)
    for (int i = tid; i < 4096; i += 512) W[4096  + i] = 0u;   // [16384,32768)
    for (int i = tid; i < 2048; i += 512) W[12288 + i] = 0u;   // [49152,57344)
  }
  __syncthreads();

  // ---- stage cs -> h1 buf1 (f16, cols 0..127, zeros >=96)
  {
    int r = tid >> 3, cg = (tid & 7) * 16;
    #pragma unroll
    for (int u = 0; u < 2; ++u){
      f16x8 V;
      #pragma unroll
      for (int q4 = 0; q4 < 2; ++q4){
        int col = cg + u*8 + q4*4;
        float4 v = make_float4(0.f,0.f,0.f,0.f);
        if (col < CS) v = *(const float4*)&cs[(size_t)(rowBase + r)*CS + col];
        V[q4*4+0]=(_Float16)v.x; V[q4*4+1]=(_Float16)v.y;
        V[q4*4+2]=(_Float16)v.z; V[q4*4+3]=(_Float16)v.w;
      }
      int ad = OH1 + 16384 + r*256 + (((cg + u*8)*2) ^ ((r & 7) << 4));
      *(f16x8*)(L + ad) = V;
    }
  }
  // x(0) -> x buf0
  if (tid < 192){
    float4 v = *(const float4*)&x[((size_t)(rowBase + xr)*T + 0)*F + xq*4];
    f16x4 w; w[0]=(_Float16)v.x; w[1]=(_Float16)v.y; w[2]=(_Float16)v.z; w[3]=(_Float16)v.w;
    *(f16x4*)(L + xst) = w;
  }
  // wEff
  if (tid < 128){
    float s = 0.f;
    for (int a = 0; a < 64; ++a) s += d2w[a] * d1w[a*128 + tid];
    ((float*)(L + OWE))[tid] = s;
  } else if (tid == 128){
    float s = 0.f;
    for (int a = 0; a < 64; ++a) s += d2w[a] * d1b[a];
    ((float*)(L + OWE))[128] = s + d2b[0];
  }
  // kC (per-gate folded bias constants)
  if (lg == 0){
    f32x4 c1k, c0k;
    #pragma unroll
    for (int g = 0; g < 4; ++g){
      float f = (g == 2) ? PL2E2 : NL2E;
      c1k[g] = f * (b1i[g*128 + n1 + lr] + b1h[g*128 + n1 + lr]);
      c0k[g] = f * (b0i[g*64  + n0 + lr] + b0h[g*64  + n0 + lr]);
    }
    *(f32x4*)(L + kadC1) = c1k;
    *(f32x4*)(L + kadC0) = c0k;   // waves 0-3/4-7 duplicate same data: benign
  }
  // W0x, W0h fragments -> LDS
  #pragma unroll
  for (int k = 0; k < 4; ++k){
    int i = tid + k*512;
    *(long*)(L + OWX + i*8) = *(const long*)(ws + Q0XOFF + i*8);
  }
  #pragma unroll
  for (int k = 0; k < 8; ++k){
    int i = tid + k*512;
    *(long*)(L + OWH + i*8) = *(const long*)(ws + Q0HOFF + i*8);
  }
  // W1 fragments -> registers
  f16x8 WB1[4][6];
  #pragma unroll
  for (int g = 0; g < 4; ++g)
    #pragma unroll
    for (int ks = 0; ks < 6; ++ks)
      WB1[g][ks] = *(const f16x8*)(ws + Q1OFF + ((long)(((wave*4+g)*6+ks)*64 + lane))*16);
  __syncthreads();

  // ---- init GEMMs (cs in h1 buf1) -> c-states in LDS
  {
    const f32x4 Zf = {0.f,0.f,0.f,0.f};
    float bb2 = fc2b[n1 + lr];
    #pragma unroll
    for (int mt = 0; mt < 4; ++mt){
      f32x4 a = Zf;
      #pragma unroll
      for (int ks = 0; ks < 3; ++ks){
        f16x8 A = *(const f16x8*)(L + ((rb1 ^ (ks << 6)) + 16384 + mt*4096));
        f16x8 B = *(const f16x8*)(ws + QF2OFF + ((long)((wave*3+ks)*64 + lane))*16);
        a = MFMA16(A, B, a);
      }
      #pragma unroll
      for (int e = 0; e < 4; ++e)
        *(float*)(L + cbase + (mt*4 + e)*2048) = a[e] + bb2;
    }
    float bb1 = fc1b[n0 + lr];
    #pragma unroll
    for (int mt = 0; mt < 2; ++mt){
      f32x4 a = Zf;
      #pragma unroll
      for (int ks = 0; ks < 3; ++ks){
        f16x8 A = *(const f16x8*)(L + ((rb1 ^ (ks << 6)) + 16384 + mB0*256 + mt*4096));
        f16x8 B = *(const f16x8*)(ws + QF1OFF + ((long)((grp*3+ks)*64 + lane))*16);
        a = MFMA16(A, B, a);
      }
      #pragma unroll
      for (int e = 0; e < 4; ++e)
        *(float*)(L + cbase + ((16 + mt*4) + e)*2048) = a[e] + bb1;
    }
  }
  __syncthreads();

  // ---- tile lambdas
  auto l1_one = [&](int mt, int p8, int p16, int q16){
    const f32x4 Zf = {0.f,0.f,0.f,0.f};
    f32x4 kC = *(const f32x4*)(L + kadC1);
    f16x8 H = *(const f16x8*)(L + (rb0 + p8 + mt*2048));
    f32x4 a0 = MFMA16(H, WB1[0][0], Zf);
    f32x4 a1 = MFMA16(H, WB1[1][0], Zf);
    f32x4 a2 = MFMA16(H, WB1[2][0], Zf);
    f32x4 a3 = MFMA16(H, WB1[3][0], Zf);
    H = *(const f16x8*)(L + ((rb0 ^ 64) + p8 + mt*2048));
    a0 = MFMA16(H, WB1[0][1], a0); a1 = MFMA16(H, WB1[1][1], a1);
    a2 = MFMA16(H, WB1[2][1], a2); a3 = MFMA16(H, WB1[3][1], a3);
    #pragma unroll
    for (int ks = 0; ks < 4; ++ks){
      H = *(const f16x8*)(L + ((rb1 ^ (ks << 6)) + p16 + mt*4096));
      a0 = MFMA16(H, WB1[0][2+ks], a0); a1 = MFMA16(H, WB1[1][2+ks], a1);
      a2 = MFMA16(H, WB1[2][2+ks], a2); a3 = MFMA16(H, WB1[3][2+ks], a3);
    }
    const int sb = cst1 + q16 + mt*4096;
    #pragma unroll
    for (int e = 0; e < 4; ++e){
      float t0 = fmaf(a0[e], NL2E,  kC[0]);
      float t1 = fmaf(a1[e], NL2E,  kC[1]);
      float t2 = fmaf(a2[e], PL2E2, kC[2]);
      float t3 = fmaf(a3[e], NL2E,  kC[3]);
      float cc = *(const float*)(L + cbase + (mt*4 + e)*2048);
      float h = cellupd(t0, t1, t2, t3, cc);
      *(float*)(L + cbase + (mt*4 + e)*2048) = cc;
      *(_Float16*)(L + ((sb + e*256) ^ (e << 4))) = (_Float16)h;
    }
  };

  auto l0_one = [&](int mt, int p8, int px, int q8){
    const f32x4 Zf = {0.f,0.f,0.f,0.f};
    f32x4 kC = *(const f32x4*)(L + kadC0);
    f16x8 X  = *(const f16x8*)(L + (xrdb + px + mt*1024));
    f16x8 H0 = *(const f16x8*)(L + (rb0w + p8 + mt*2048));
    f16x8 H1 = *(const f16x8*)(L + ((rb0w ^ 64) + p8 + mt*2048));
    f32x4 a0, a1, a2, a3;
    {
      f16x8 W0 = *(const f16x8*)(L + owhb + 0*2048);
      f16x8 W1 = *(const f16x8*)(L + owhb + 0*2048 + 1024);
      f16x8 Wx = *(const f16x8*)(L + owxb + 0*1024);
      a0 = MFMA16(H0, W0, Zf); a0 = MFMA16(H1, W1, a0); a0 = MFMA16(X, Wx, a0);
    }
    {
      f16x8 W0 = *(const f16x8*)(L + owhb + 1*2048);
      f16x8 W1 = *(const f16x8*)(L + owhb + 1*2048 + 1024);
      f16x8 Wx = *(const f16x8*)(L + owxb + 1*1024);
      a1 = MFMA16(H0, W0, Zf); a1 = MFMA16(H1, W1, a1); a1 = MFMA16(X, Wx, a1);
    }
    {
      f16x8 W0 = *(const f16x8*)(L + owhb + 2*2048);
      f16x8 W1 = *(const f16x8*)(L + owhb + 2*2048 + 1024);
      f16x8 Wx = *(const f16x8*)(L + owxb + 2*1024);
      a2 = MFMA16(H0, W0, Zf); a2 = MFMA16(H1, W1, a2); a2 = MFMA16(X, Wx, a2);
    }
    {
      f16x8 W0 = *(const f16x8*)(L + owhb + 3*2048);
      f16x8 W1 = *(const f16x8*)(L + owhb + 3*2048 + 1024);
      f16x8 Wx = *(const f16x8*)(L + owxb + 3*1024);
      a3 = MFMA16(H0, W0, Zf); a3 = MFMA16(H1, W1, a3); a3 = MFMA16(X, Wx, a3);
    }
    const int sb = cst0 + q8 + mt*2048;
    #pragma unroll
    for (int e = 0; e < 4; ++e){
      float t0 = fmaf(a0[e], NL2E,  kC[0]);
      float t1 = fmaf(a1[e], NL2E,  kC[1]);
      float t2 = fmaf(a2[e], PL2E2, kC[2]);
      float t3 = fmaf(a3[e], NL2E,  kC[3]);
      float cc = *(const float*)(L + cbase + ((16 + mt*4) + e)*2048);
      float h = cellupd(t0, t1, t2, t3, cc);
      *(float*)(L + cbase + ((16 + mt*4) + e)*2048) = cc;
      *(_Float16*)(L + ((sb + e*128) ^ (e << 4))) = (_Float16)h;
    }
  };

  // ---- pre-loop: L0(0): h0(-1)=zeros(buf1), x(0)(buf0) -> h0(0)->buf0; stage x(1)->buf1
  {
    float4 xv; const bool doX = tid < 192;
    if (doX) xv = *(const float4*)&x[((size_t)(rowBase + xr)*T + 1)*F + xq*4];
    l0_one(0, 8192, 0, 0);
    l0_one(1, 8192, 0, 0);
    if (doX){
      f16x4 w; w[0]=(_Float16)xv.x; w[1]=(_Float16)xv.y; w[2]=(_Float16)xv.z; w[3]=(_Float16)xv.w;
      *(f16x4*)(L + xst + 4096) = w;
    }
    __syncthreads();
  }

  // ---- main loop: M(i) = L1(i) + L0(i+1); 1 barrier/step
  for (int j = 0; j < 7; ++j){
    { // M(2j): reads buf0 (h0,h1), x buf1; writes buf1; stage x(2j+2)->buf0
      float4 xv; const bool doX = tid < 192;
      if (doX) xv = *(const float4*)&x[((size_t)(rowBase + xr)*T + (2*j + 2))*F + xq*4];
      l1_one(0, 0, 0, 16384);
      l1_one(1, 0, 0, 16384);
      l0_one(0, 0, 4096, 8192);
      l1_one(2, 0, 0, 16384);
      l0_one(1, 0, 4096, 8192);
      l1_one(3, 0, 0, 16384);
      if (doX){
        f16x4 w; w[0]=(_Float16)xv.x; w[1]=(_Float16)xv.y; w[2]=(_Float16)xv.z; w[3]=(_Float16)xv.w;
        *(f16x4*)(L + xst) = w;
      }
      __syncthreads();
    }
    { // M(2j+1): reads buf1, x buf0; writes buf0; stage x(2j+3)->buf1 (j<6)
      float4 xv; const bool doX = (j < 6) && (tid < 192);
      if (doX) xv = *(const float4*)&x[((size_t)(rowBase + xr)*T + (2*j + 3))*F + xq*4];
      l1_one(0, 8192, 16384, 0);
      l1_one(1, 8192, 16384, 0);
      l0_one(0, 8192, 0, 0);
      l1_one(2, 8192, 16384, 0);
      l0_one(1, 8192, 0, 0);
      l1_one(3, 8192, 16384, 0);
      if (doX){
        f16x4 w; w[0]=(_Float16)xv.x; w[1]=(_Float16)xv.y; w[2]=(_Float16)xv.z; w[3]=(_Float16)xv.w;
        *(f16x4*)(L + xst + 4096) = w;
      }
      __syncthreads();
    }
  }

  // ---- final: L1(14) (reads buf0) -> h1(15) into buf1
  {
    l1_one(0, 0, 0, 16384);
    l1_one(1, 0, 0, 16384);
    l1_one(2, 0, 0, 16384);
    l1_one(3, 0, 0, 16384);
    __syncthreads();
  }

  // ---- epilogue: pred = h1 . w_eff + b_eff (h1 f16 in buf1)
  {
    int r = tid >> 3, s = tid & 7;
    const float* wE = (const float*)(L + OWE);
    float sum = 0.f;
    #pragma unroll
    for (int cc = 0; cc < 16; ++cc){
      int c = s*16 + cc;
      const char* pe = L + OH1 + 16384 + r*256 + ((c*2) ^ ((r & 7) << 4));
      sum += (float)(*(const _Float16*)pe) * wE[c];
    }
    sum += __shfl_down(sum, 4);
    sum += __shfl_down(sum, 2);
    sum += __shfl_down(sum, 1);
    if (s == 0) out[rowBase + r] = sum + wE[128];
  }
}

extern "C" void kernel_launch(void* const* d_in, const int* in_sizes, int n_in,
                              void* d_out, int out_size, void* d_ws, size_t ws_size,
                              hipStream_t stream) {
  const float* x    = (const float*)d_in[0];
  const float* cs   = (const float*)d_in[1];
  const float* fc1w = (const float*)d_in[2];
  const float* fc1b = (const float*)d_in[3];
  const float* fc2w = (const float*)d_in[4];
  const float* fc2b = (const float*)d_in[5];
  const float* w0i  = (const float*)d_in[6];
  const float* w0h  = (const float*)d_in[7];
  const float* b0i  = (const float*)d_in[8];
  const float* b0h  = (const float*)d_in[9];
  const float* w1i  = (const float*)d_in[10];
  const float* w1h  = (const float*)d_in[11];
  const float* b1i  = (const float*)d_in[12];
  const float* b1h  = (const float*)d_in[13];
  const float* d1w  = (const float*)d_in[14];
  const float* d1b  = (const float*)d_in[15];
  const float* d2w  = (const float*)d_in[16];
  const float* d2b  = (const float*)d_in[17];

  char* ws = (char*)d_ws;
  prequant<<<960, 64, 0, stream>>>(fc1w, fc2w, w0i, w0h, w1i, w1h, ws);

  const int Btot = in_sizes[0] / (T * F);   // 131072
  const int grid = Btot / R;                // 2048
  caurec<<<grid, 512, 0, stream>>>(x, cs, fc1b, fc2b, b0i, b0h, b1i, b1h,
                                   d1w, d1b, d2w, d2b, ws, (float*)d_out);
}